// Round 2
// baseline (88.091 us; speedup 1.0000x reference)
//
#include <hip/hip_runtime.h>
#include <math.h>

#define NQ   4
#define NH   8
#define NL   2
#define DIM  16   // 2^NQ
#define EMB  32
#define TPB  256  // tokens per block

#define LO_SCALE 4096.0f          // 2^12: lo-part pre-scale (keeps f16 normal)
#define LO_INV   (1.0f/4096.0f)

typedef _Float16 f16x8  __attribute__((ext_vector_type(8)));
typedef float    f32x16 __attribute__((ext_vector_type(16)));

// ---------------------------------------------------------------------------
// Setup kernel (1 block, 128 threads):
//  (a) threads 0..127: build per-head 16x16 circuit unitary U, emit as MFMA
//      A-fragments [Ur;Ui] (32x16) for v_mfma_f32_32x32x16_f16, f16 hi/lo
//      split: Ahi[8h][64 lane][8e] at ws halfs [0,4096), Alo at [4096,8192).
//  (b) threads 0..63: emit W^T as MFMA B-fragments (N=e_out, K=k 0..31 in two
//      K=16 frags), f16 hi/lo: per lane 4 x f16x8 {Wh0,Wh1,Wl0,Wl1} at halfs
//      [8192, 8192+2048).
// ---------------------------------------------------------------------------
__global__ void build_unitaries_kernel(const float* __restrict__ params,
                                       const float* __restrict__ W,
                                       float* __restrict__ Uws) {
    int tid = threadIdx.x;          // 0..127
    int h   = tid >> 4;
    int col = tid & 15;

    float re[DIM], im[DIM];
#pragma unroll
    for (int j = 0; j < DIM; ++j) { re[j] = (j == col) ? 1.f : 0.f; im[j] = 0.f; }

#pragma unroll
    for (int l = 0; l < NL; ++l) {
#pragma unroll
        for (int q = 0; q < NQ; ++q) {
            const float* p = params + ((h * NL + l) * NQ + q) * 3;
            const int m = 1 << (3 - q);      // compile-time after unroll
            // RX
            {
                float s, c; __sincosf(0.5f * p[0], &s, &c);
#pragma unroll
                for (int j = 0; j < DIM; ++j) {
                    if (j & m) continue;
                    const int j1 = j | m;
                    float r0 = re[j], i0 = im[j], r1 = re[j1], i1 = im[j1];
                    re[j]  = c * r0 + s * i1;
                    im[j]  = c * i0 - s * r1;
                    re[j1] = s * i0 + c * r1;
                    im[j1] = -s * r0 + c * i1;
                }
            }
            // RY
            {
                float s, c; __sincosf(0.5f * p[1], &s, &c);
#pragma unroll
                for (int j = 0; j < DIM; ++j) {
                    if (j & m) continue;
                    const int j1 = j | m;
                    float r0 = re[j], i0 = im[j], r1 = re[j1], i1 = im[j1];
                    re[j]  = c * r0 - s * r1;
                    im[j]  = c * i0 - s * i1;
                    re[j1] = s * r0 + c * r1;
                    im[j1] = s * i0 + c * i1;
                }
            }
            // RZ
            {
                float s, c; __sincosf(0.5f * p[2], &s, &c);
#pragma unroll
                for (int j = 0; j < DIM; ++j) {
                    if (j & m) continue;
                    const int j1 = j | m;
                    float r0 = re[j], i0 = im[j], r1 = re[j1], i1 = im[j1];
                    re[j]  = c * r0 + s * i0;
                    im[j]  = c * i0 - s * r0;
                    re[j1] = c * r1 - s * i1;
                    im[j1] = c * i1 + s * r1;
                }
            }
        }
        // CNOT ring: (0,1),(1,2),(2,3),(3,0)
#pragma unroll
        for (int e = 0; e < NQ; ++e) {
            const int cm = 1 << (3 - e), tm = 1 << (3 - ((e + 1) & 3));
#pragma unroll
            for (int j = 0; j < DIM; ++j) {
                if ((j & cm) && !(j & tm)) {
                    const int j1 = j | tm;
                    float tr = re[j]; re[j] = re[j1]; re[j1] = tr;
                    float ti = im[j]; im[j] = im[j1]; im[j1] = ti;
                }
            }
        }
    }

    // ---- (a) emit U A-fragments ----
    _Float16* Ah = (_Float16*)Uws;        // 4096 halfs
    _Float16* Al = Ah + 4096;             // 4096 halfs
    const int khigh = col >> 3, e = col & 7;
#pragma unroll
    for (int j = 0; j < DIM; ++j) {
        {   // real part -> M-row j
            const float v = re[j];
            const _Float16 h16 = (_Float16)v;
            const float lo = (v - (float)h16) * LO_SCALE;
            const int lane = j + 32 * khigh;
            Ah[(h * 64 + lane) * 8 + e] = h16;
            Al[(h * 64 + lane) * 8 + e] = (_Float16)lo;
        }
        {   // imag part -> M-row 16+j
            const float v = im[j];
            const _Float16 h16 = (_Float16)v;
            const float lo = (v - (float)h16) * LO_SCALE;
            const int lane = 16 + j + 32 * khigh;
            Ah[(h * 64 + lane) * 8 + e] = h16;
            Al[(h * 64 + lane) * 8 + e] = (_Float16)lo;
        }
    }

    // ---- (b) emit W^T B-fragments ----
    if (tid < 64) {
        const int eo = tid & 31, kh = tid >> 5;
        _Float16* Wf = ((_Float16*)Uws) + 8192 + tid * 32;
#pragma unroll
        for (int j = 0; j < 8; ++j) {
            const float v0 = W[eo * EMB + kh * 8 + j];          // k = kh*8+j
            const float v1 = W[eo * EMB + 16 + kh * 8 + j];     // k = 16+kh*8+j
            const _Float16 h0 = (_Float16)v0;
            const _Float16 h1 = (_Float16)v1;
            Wf[j]      = h0;
            Wf[8 + j]  = h1;
            Wf[16 + j] = (_Float16)((v0 - (float)h0) * LO_SCALE);
            Wf[24 + j] = (_Float16)((v1 - (float)h1) * LO_SCALE);
        }
    }
}

// ---------------------------------------------------------------------------
// Main: block = 512 threads = 8 waves, 256 tokens/block.
// Phase 1: wave h = head h, 8 groups of 32 tokens. Per group: 3x
//   mfma_f32_32x32x16_f16 ([Ur;Ui] hi/lo x psi0 hi/lo), lane-local pj,
//   cross-half shfl, ev -> LDS evs[k][t] (stride 256, conflict-free).
// Phase 2: wave w = token-group w. out^T = ev^T @ W^T via 6 MFMA
//   (K=32 split into 2, hi/lo 3-pass). C layout col=lane&31 = EMBED axis ->
//   each store instruction writes two contiguous 128B out rows. No Wt LDS.
// ---------------------------------------------------------------------------
__global__ __launch_bounds__(512, 4)
void qmha_kernel(const float* __restrict__ x,
                 const float* __restrict__ Uws,
                 const float* __restrict__ bvec,
                 float* __restrict__ out,
                 int ntok) {
    __shared__ float evs[EMB * TPB];   // evs[k][t], k = h*4+q, stride 256; 32 KB

    const int tid  = threadIdx.x;
    const int tok0 = blockIdx.x * TPB;
    const int lane = tid & 63;
    const int lh   = lane & 31;        // MFMA column slot
    const int hi   = lane >> 5;        // K-half

    f32x16 zz;                          // persistent zero C operand
#pragma unroll
    for (int i = 0; i < 16; ++i) zz[i] = 0.f;

    // ---- phase 1: quantum circuit via MFMA ----
    {
        const int h = __builtin_amdgcn_readfirstlane(tid >> 6);  // wave = head

        const _Float16* Ahp = (const _Float16*)Uws;
        const _Float16* Alp = Ahp + 4096;
        const f16x8 Afh = *(const f16x8*)(Ahp + (h * 64 + lane) * 8);
        const f16x8 Afl = *(const f16x8*)(Alp + (h * 64 + lane) * 8);

#pragma unroll 2
        for (int g = 0; g < 8; ++g) {
            const int t    = g * 32 + lh;
            const int tok  = tok0 + t;
            const int tokc = (tok < ntok) ? tok : (ntok - 1);

            const float4 xa = *(const float4*)(x + (size_t)tokc * EMB + h * NQ);
            float c0, s0, c1, s1, c2, s2, c3, s3;
            __sincosf(0.5f * xa.x, &s0, &c0);
            __sincosf(0.5f * xa.y, &s1, &c1);
            __sincosf(0.5f * xa.z, &s2, &c2);
            __sincosf(0.5f * xa.w, &s3, &c3);

            // psi0[k] for k = hi*8 + e only
            const float f  = hi ? s0 : c0;
            const float pA = f * c1, pB = f * s1;
            const float p23[4] = {c2 * c3, c2 * s3, s2 * c3, s2 * s3};

            f16x8 bh, bl;
#pragma unroll
            for (int e = 0; e < 8; ++e) {
                const float av = ((e >> 2) ? pB : pA) * p23[e & 3];
                const _Float16 ah16 = (_Float16)av;
                bh[e] = ah16;
                bl[e] = (_Float16)((av - (float)ah16) * LO_SCALE);
            }

            f32x16 accH = __builtin_amdgcn_mfma_f32_32x32x16_f16(Afh, bh, zz, 0, 0, 0);
            f32x16 accL = __builtin_amdgcn_mfma_f32_32x32x16_f16(Afl, bh, zz, 0, 0, 0);
            accL = __builtin_amdgcn_mfma_f32_32x32x16_f16(Afh, bl, accL, 0, 0, 0);

            // pj for j = (r&3) + 8*(r>>2) + 4*hi
            float pj[8];
#pragma unroll
            for (int r = 0; r < 8; ++r) {
                const float ar = fmaf(accL[r],     LO_INV, accH[r]);
                const float ai = fmaf(accL[r + 8], LO_INV, accH[r + 8]);
                pj[r] = ar * ar + ai * ai;
            }
            const float s01 = pj[0] + pj[1], s23 = pj[2] + pj[3];
            const float s45 = pj[4] + pj[5], s67 = pj[6] + pj[7];
            const float sa = s01 + s23, sb = s45 + s67;
            float ev0 = sa - sb;
            const float tot = sa + sb;
            float ev1 = hi ? -tot : tot;
            float ev2 = (s01 + s45) - (s23 + s67);
            float ev3 = (pj[0] - pj[1]) + (pj[2] - pj[3]) +
                        (pj[4] - pj[5]) + (pj[6] - pj[7]);
            ev0 += __shfl_xor(ev0, 32);
            ev1 += __shfl_xor(ev1, 32);
            ev2 += __shfl_xor(ev2, 32);
            ev3 += __shfl_xor(ev3, 32);

            if (hi == 0 && tok < ntok) {
                evs[(h * 4 + 0) * TPB + t] = ev0;
                evs[(h * 4 + 1) * TPB + t] = ev1;
                evs[(h * 4 + 2) * TPB + t] = ev2;
                evs[(h * 4 + 3) * TPB + t] = ev3;
            }
        }
    }
    __syncthreads();

    // ---- phase 2: out^T = ev^T @ W^T via MFMA ----
    {
        const int w = tid >> 6;            // wave = token-group
        const _Float16* Wf = ((const _Float16*)Uws) + 8192 + lane * 32;
        const f16x8 Wh0 = *(const f16x8*)(Wf + 0);
        const f16x8 Wh1 = *(const f16x8*)(Wf + 8);
        const f16x8 Wl0 = *(const f16x8*)(Wf + 16);
        const f16x8 Wl1 = *(const f16x8*)(Wf + 24);
        const float bias = bvec[lh];

        // A-frags: ev[k][t], lane row = t (lh), k-half = hi
        const float* evp = evs + w * 32 + lh;
        f16x8 Ah0, Ah1, Al0, Al1;
#pragma unroll
        for (int e = 0; e < 8; ++e) {
            const int k0 = hi * 8 + e;
            const float v0 = evp[k0 * TPB];
            const float v1 = evp[(16 + k0) * TPB];
            const _Float16 a0 = (_Float16)v0;
            const _Float16 a1 = (_Float16)v1;
            Ah0[e] = a0;
            Ah1[e] = a1;
            Al0[e] = (_Float16)((v0 - (float)a0) * LO_SCALE);
            Al1[e] = (_Float16)((v1 - (float)a1) * LO_SCALE);
        }

        f32x16 aH = __builtin_amdgcn_mfma_f32_32x32x16_f16(Ah0, Wh0, zz, 0, 0, 0);
        aH = __builtin_amdgcn_mfma_f32_32x32x16_f16(Ah1, Wh1, aH, 0, 0, 0);
        f32x16 aL = __builtin_amdgcn_mfma_f32_32x32x16_f16(Al0, Wh0, zz, 0, 0, 0);
        aL = __builtin_amdgcn_mfma_f32_32x32x16_f16(Al1, Wh1, aL, 0, 0, 0);
        aL = __builtin_amdgcn_mfma_f32_32x32x16_f16(Ah0, Wl0, aL, 0, 0, 0);
        aL = __builtin_amdgcn_mfma_f32_32x32x16_f16(Ah1, Wl1, aL, 0, 0, 0);

        // C: col = lane&31 = e_out, row = token within group
#pragma unroll
        for (int r = 0; r < 16; ++r) {
            const int trow = (r & 3) + 8 * (r >> 2) + 4 * hi;
            const int tok  = tok0 + w * 32 + trow;
            if (tok < ntok) {
                out[(size_t)tok * EMB + lh] =
                    fmaf(aL[r], LO_INV, aH[r]) + bias;
            }
        }
    }
}

extern "C" void kernel_launch(void* const* d_in, const int* in_sizes, int n_in,
                              void* d_out, int out_size, void* d_ws, size_t ws_size,
                              hipStream_t stream) {
    const float* x      = (const float*)d_in[0];
    const float* params = (const float*)d_in[1];
    const float* W_out  = (const float*)d_in[2];
    const float* b_out  = (const float*)d_in[3];
    float*       out    = (float*)d_out;
    float*       Uws    = (float*)d_ws;   // 10240 halfs = 20.5 KB (U + W frags)

    const int ntok = in_sizes[0] / EMB;   // B*S = 131072

    hipLaunchKernelGGL(build_unitaries_kernel, dim3(1), dim3(128), 0, stream,
                       params, W_out, Uws);

    const int blocks = (ntok + TPB - 1) / TPB;
    hipLaunchKernelGGL(qmha_kernel, dim3(blocks), dim3(512), 0, stream,
                       x, Uws, b_out, out, ntok);
}

// Round 3
// 87.504 us; speedup vs baseline: 1.0067x; 1.0067x over previous
//
#include <hip/hip_runtime.h>
#include <math.h>

#define NQ   4
#define NH   8
#define NL   2
#define DIM  16   // 2^NQ
#define EMB  32
#define TPB  256  // tokens per block

#define LO_SCALE 4096.0f          // 2^12: lo-part pre-scale (keeps f16 normal)
#define LO_INV   (1.0f/4096.0f)
#define HSTR 520                  // halfs per head plane: 512 + 8 pad (bank skew)

typedef _Float16 f16x8  __attribute__((ext_vector_type(8)));
typedef float    f32x16 __attribute__((ext_vector_type(16)));

// ---------------------------------------------------------------------------
// Single fused kernel. 512 threads = 8 waves, 256 tokens/block.
//  Stage 0 (threads 0..127): build per-head 16x16 circuit unitary in regs
//    (thread = (head h, basis column col), fully unrolled), emit as
//    f16 hi/lo MFMA A-fragments [Ur;Ui] (32x16) into LDS. No global ws ->
//    no dependency on the harness's 256MB workspace poison fill, and no
//    second kernel launch/drain.
//  Phase 1: wave h = head h, 8 groups of 32 tokens; 3x mfma_f32_32x32x16_f16
//    (hi*hi, lo*hi, hi*lo w/ 2^12 pre-scale), lane-local pj, ev -> LDS.
//  Phase 2: wave w = token-group w; out^T = ev^T @ W^T via 6 MFMA, W frags
//    built per-wave from global W (4KB, cache-hot). Stores: per r, both
//    lane-halves write contiguous 128B rows of out.
// ---------------------------------------------------------------------------
__global__ __launch_bounds__(512, 4)
void qmha_fused(const float* __restrict__ x,
                const float* __restrict__ params,
                const float* __restrict__ W,
                const float* __restrict__ bvec,
                float* __restrict__ out,
                int ntok) {
    __shared__ _Float16 AfH[NH * HSTR];   // 8320 halfs
    __shared__ _Float16 AfL[NH * HSTR];
    __shared__ float    evs[EMB * TPB];   // evs[k][t], stride 256; 32 KB

    const int tid  = threadIdx.x;
    const int tok0 = blockIdx.x * TPB;
    const int lane = tid & 63;
    const int lh   = lane & 31;        // MFMA column slot
    const int hi   = lane >> 5;        // K-half
    const int wv   = tid >> 6;         // wave id

    f32x16 zz;                          // persistent zero C operand
#pragma unroll
    for (int i = 0; i < 16; ++i) zz[i] = 0.f;

    // ---- early x load (group 0) so HBM latency hides under the U-build ----
    float4 xa_cur;
    {
        int tk = tok0 + lh; if (tk >= ntok) tk = ntok - 1;
        xa_cur = *(const float4*)(x + (size_t)tk * EMB + wv * NQ);
    }

    // ---- stage 0: in-block unitary build (threads 0..127) ----
    if (tid < 128) {
        const int h   = tid >> 4;
        const int col = tid & 15;

        float re[DIM], im[DIM];
#pragma unroll
        for (int j = 0; j < DIM; ++j) { re[j] = (j == col) ? 1.f : 0.f; im[j] = 0.f; }

#pragma unroll
        for (int l = 0; l < NL; ++l) {
#pragma unroll
            for (int q = 0; q < NQ; ++q) {
                const float* p = params + ((h * NL + l) * NQ + q) * 3;
                const int m = 1 << (3 - q);      // compile-time after unroll
                // RX
                {
                    float s, c; __sincosf(0.5f * p[0], &s, &c);
#pragma unroll
                    for (int j = 0; j < DIM; ++j) {
                        if (j & m) continue;
                        const int j1 = j | m;
                        float r0 = re[j], i0 = im[j], r1 = re[j1], i1 = im[j1];
                        re[j]  = c * r0 + s * i1;
                        im[j]  = c * i0 - s * r1;
                        re[j1] = s * i0 + c * r1;
                        im[j1] = -s * r0 + c * i1;
                    }
                }
                // RY
                {
                    float s, c; __sincosf(0.5f * p[1], &s, &c);
#pragma unroll
                    for (int j = 0; j < DIM; ++j) {
                        if (j & m) continue;
                        const int j1 = j | m;
                        float r0 = re[j], i0 = im[j], r1 = re[j1], i1 = im[j1];
                        re[j]  = c * r0 - s * r1;
                        im[j]  = c * i0 - s * i1;
                        re[j1] = s * r0 + c * r1;
                        im[j1] = s * i0 + c * i1;
                    }
                }
                // RZ
                {
                    float s, c; __sincosf(0.5f * p[2], &s, &c);
#pragma unroll
                    for (int j = 0; j < DIM; ++j) {
                        if (j & m) continue;
                        const int j1 = j | m;
                        float r0 = re[j], i0 = im[j], r1 = re[j1], i1 = im[j1];
                        re[j]  = c * r0 + s * i0;
                        im[j]  = c * i0 - s * r0;
                        re[j1] = c * r1 - s * i1;
                        im[j1] = c * i1 + s * r1;
                    }
                }
            }
            // CNOT ring: (0,1),(1,2),(2,3),(3,0)
#pragma unroll
            for (int e = 0; e < NQ; ++e) {
                const int cm = 1 << (3 - e), tm = 1 << (3 - ((e + 1) & 3));
#pragma unroll
                for (int j = 0; j < DIM; ++j) {
                    if ((j & cm) && !(j & tm)) {
                        const int j1 = j | tm;
                        float tr = re[j]; re[j] = re[j1]; re[j1] = tr;
                        float ti = im[j]; im[j] = im[j1]; im[j1] = ti;
                    }
                }
            }
        }

        // emit A-fragments into LDS (this thread owns column k=col)
        const int khigh = col >> 3, e = col & 7;
#pragma unroll
        for (int j = 0; j < DIM; ++j) {
            {   // real part -> M-row j
                const float v = re[j];
                const _Float16 h16 = (_Float16)v;
                const int ln = j + 32 * khigh;
                AfH[h * HSTR + ln * 8 + e] = h16;
                AfL[h * HSTR + ln * 8 + e] = (_Float16)((v - (float)h16) * LO_SCALE);
            }
            {   // imag part -> M-row 16+j
                const float v = im[j];
                const _Float16 h16 = (_Float16)v;
                const int ln = 16 + j + 32 * khigh;
                AfH[h * HSTR + ln * 8 + e] = h16;
                AfL[h * HSTR + ln * 8 + e] = (_Float16)((v - (float)h16) * LO_SCALE);
            }
        }
    }
    __syncthreads();

    // ---- phase 1: quantum circuit via MFMA ----
    {
        const int h = wv;   // wave = head
        const f16x8 Afh = *(const f16x8*)(AfH + h * HSTR + lane * 8);
        const f16x8 Afl = *(const f16x8*)(AfL + h * HSTR + lane * 8);

#pragma unroll 2
        for (int g = 0; g < 8; ++g) {
            // software prefetch of next group's x
            float4 xa_next = xa_cur;
            if (g < 7) {
                int tk = tok0 + (g + 1) * 32 + lh; if (tk >= ntok) tk = ntok - 1;
                xa_next = *(const float4*)(x + (size_t)tk * EMB + h * NQ);
            }

            const int t   = g * 32 + lh;
            const int tok = tok0 + t;

            float c0, s0, c1, s1, c2, s2, c3, s3;
            __sincosf(0.5f * xa_cur.x, &s0, &c0);
            __sincosf(0.5f * xa_cur.y, &s1, &c1);
            __sincosf(0.5f * xa_cur.z, &s2, &c2);
            __sincosf(0.5f * xa_cur.w, &s3, &c3);

            // psi0[k] for k = hi*8 + e only
            const float f  = hi ? s0 : c0;
            const float pA = f * c1, pB = f * s1;
            const float p23[4] = {c2 * c3, c2 * s3, s2 * c3, s2 * s3};

            f16x8 bh, bl;
#pragma unroll
            for (int e = 0; e < 8; ++e) {
                const float av = ((e >> 2) ? pB : pA) * p23[e & 3];
                const _Float16 ah16 = (_Float16)av;
                bh[e] = ah16;
                bl[e] = (_Float16)((av - (float)ah16) * LO_SCALE);
            }

            f32x16 accH = __builtin_amdgcn_mfma_f32_32x32x16_f16(Afh, bh, zz, 0, 0, 0);
            f32x16 accL = __builtin_amdgcn_mfma_f32_32x32x16_f16(Afl, bh, zz, 0, 0, 0);
            accL = __builtin_amdgcn_mfma_f32_32x32x16_f16(Afh, bl, accL, 0, 0, 0);

            // pj for j = (r&3) + 8*(r>>2) + 4*hi
            float pj[8];
#pragma unroll
            for (int r = 0; r < 8; ++r) {
                const float ar = fmaf(accL[r],     LO_INV, accH[r]);
                const float ai = fmaf(accL[r + 8], LO_INV, accH[r + 8]);
                pj[r] = ar * ar + ai * ai;
            }
            const float s01 = pj[0] + pj[1], s23 = pj[2] + pj[3];
            const float s45 = pj[4] + pj[5], s67 = pj[6] + pj[7];
            const float sa = s01 + s23, sb = s45 + s67;
            float ev0 = sa - sb;
            const float tot = sa + sb;
            float ev1 = hi ? -tot : tot;
            float ev2 = (s01 + s45) - (s23 + s67);
            float ev3 = (pj[0] - pj[1]) + (pj[2] - pj[3]) +
                        (pj[4] - pj[5]) + (pj[6] - pj[7]);
            ev0 += __shfl_xor(ev0, 32);
            ev1 += __shfl_xor(ev1, 32);
            ev2 += __shfl_xor(ev2, 32);
            ev3 += __shfl_xor(ev3, 32);

            if (hi == 0 && tok < ntok) {
                evs[(h * 4 + 0) * TPB + t] = ev0;
                evs[(h * 4 + 1) * TPB + t] = ev1;
                evs[(h * 4 + 2) * TPB + t] = ev2;
                evs[(h * 4 + 3) * TPB + t] = ev3;
            }
            xa_cur = xa_next;
        }
    }
    __syncthreads();

    // ---- phase 2: out^T = ev^T @ W^T via MFMA ----
    {
        const int w = wv;                  // wave = token-group
        // W fragments straight from global (4KB, L1/L2-hot), f16 hi/lo split
        const float* wp = W + lh * EMB + hi * 8;
        float wa[8], wb[8];
        {
            const float4 a0 = *(const float4*)(wp + 0);
            const float4 a1 = *(const float4*)(wp + 4);
            const float4 b0 = *(const float4*)(wp + 16);
            const float4 b1 = *(const float4*)(wp + 20);
            wa[0]=a0.x; wa[1]=a0.y; wa[2]=a0.z; wa[3]=a0.w;
            wa[4]=a1.x; wa[5]=a1.y; wa[6]=a1.z; wa[7]=a1.w;
            wb[0]=b0.x; wb[1]=b0.y; wb[2]=b0.z; wb[3]=b0.w;
            wb[4]=b1.x; wb[5]=b1.y; wb[6]=b1.z; wb[7]=b1.w;
        }
        f16x8 Wh0, Wl0, Wh1, Wl1;
#pragma unroll
        for (int e = 0; e < 8; ++e) {
            _Float16 hh = (_Float16)wa[e];
            Wh0[e] = hh; Wl0[e] = (_Float16)((wa[e] - (float)hh) * LO_SCALE);
            hh = (_Float16)wb[e];
            Wh1[e] = hh; Wl1[e] = (_Float16)((wb[e] - (float)hh) * LO_SCALE);
        }
        const float bias = bvec[lh];

        // A-frags: ev[k][t], lane row = t (lh), k-half = hi
        const float* evp = evs + w * 32 + lh;
        f16x8 Ah0, Ah1, Al0, Al1;
#pragma unroll
        for (int e = 0; e < 8; ++e) {
            const int k0 = hi * 8 + e;
            const float v0 = evp[k0 * TPB];
            const float v1 = evp[(16 + k0) * TPB];
            const _Float16 a0 = (_Float16)v0;
            const _Float16 a1 = (_Float16)v1;
            Ah0[e] = a0;
            Ah1[e] = a1;
            Al0[e] = (_Float16)((v0 - (float)a0) * LO_SCALE);
            Al1[e] = (_Float16)((v1 - (float)a1) * LO_SCALE);
        }

        f32x16 aH = __builtin_amdgcn_mfma_f32_32x32x16_f16(Ah0, Wh0, zz, 0, 0, 0);
        aH = __builtin_amdgcn_mfma_f32_32x32x16_f16(Ah1, Wh1, aH, 0, 0, 0);
        f32x16 aL = __builtin_amdgcn_mfma_f32_32x32x16_f16(Al0, Wh0, zz, 0, 0, 0);
        aL = __builtin_amdgcn_mfma_f32_32x32x16_f16(Al1, Wh1, aL, 0, 0, 0);
        aL = __builtin_amdgcn_mfma_f32_32x32x16_f16(Ah0, Wl0, aL, 0, 0, 0);
        aL = __builtin_amdgcn_mfma_f32_32x32x16_f16(Ah1, Wl1, aL, 0, 0, 0);

        // C: col = lane&31 = e_out, row = token within group
#pragma unroll
        for (int r = 0; r < 16; ++r) {
            const int trow = (r & 3) + 8 * (r >> 2) + 4 * hi;
            const int tok  = tok0 + w * 32 + trow;
            if (tok < ntok) {
                out[(size_t)tok * EMB + lh] =
                    fmaf(aL[r], LO_INV, aH[r]) + bias;
            }
        }
    }
}

extern "C" void kernel_launch(void* const* d_in, const int* in_sizes, int n_in,
                              void* d_out, int out_size, void* d_ws, size_t ws_size,
                              hipStream_t stream) {
    const float* x      = (const float*)d_in[0];
    const float* params = (const float*)d_in[1];
    const float* W_out  = (const float*)d_in[2];
    const float* b_out  = (const float*)d_in[3];
    float*       out    = (float*)d_out;
    (void)d_ws; (void)ws_size;            // workspace deliberately untouched

    const int ntok = in_sizes[0] / EMB;   // B*S = 131072

    const int blocks = (ntok + TPB - 1) / TPB;
    hipLaunchKernelGGL(qmha_fused, dim3(blocks), dim3(512), 0, stream,
                       x, params, W_out, b_out, out, ntok);
}